// Round 1
// 315.680 us; speedup vs baseline: 1.0013x; 1.0013x over previous
//
#include <hip/hip_runtime.h>
#include <hip/hip_bf16.h>
#include <stdint.h>
#include <stddef.h>

typedef unsigned short u16;
typedef __attribute__((ext_vector_type(8))) short short8;
typedef __attribute__((ext_vector_type(4))) float f32x4;
typedef __attribute__((ext_vector_type(16))) float f32x16;

#define NB 4
#define NL 1024
#define ND 768
#define NH 12
#define NDH 64

__device__ __forceinline__ u16 f2bf(float f) {
  __hip_bfloat16 h = __float2bfloat16(f);
  return *reinterpret_cast<u16*>(&h);
}
__device__ __forceinline__ float bf2f(u16 u) {
  __hip_bfloat16 h;
  *reinterpret_cast<u16*>(&h) = u;
  return __bfloat162float(h);
}

// async global->LDS, 16B per lane. LDS dest is wave-uniform base; HW adds lane*16.
__device__ __forceinline__ void load16_to_lds(const u16* g, u16* l) {
  __builtin_amdgcn_global_load_lds(
      (__attribute__((address_space(1))) void*)(uintptr_t)g,
      (__attribute__((address_space(3))) void*)(uint32_t)(uintptr_t)l,
      16, 0, 0);
}

// ---------------- cast fp32 -> bf16 (vectorized) ----------------
__global__ __launch_bounds__(256) void cast_bf16_kernel(const float* __restrict__ in,
                                                        u16* __restrict__ out, int n4) {
  int i = blockIdx.x * 256 + threadIdx.x;
  int stride = gridDim.x * 256;
  for (; i < n4; i += stride) {
    float4 f = ((const float4*)in)[i];
    ushort4 o;
    o.x = f2bf(f.x); o.y = f2bf(f.y); o.z = f2bf(f.z); o.w = f2bf(f.w);
    ((ushort4*)out)[i] = o;
  }
}

// ---------------- transpose+cast (q and k merged): out[h][c][r] = in[h][r][c] ----------------
__global__ __launch_bounds__(256) void transpose_cast2_kernel(const float* __restrict__ qI,
                                                              const float* __restrict__ kI,
                                                              u16* __restrict__ qT,
                                                              u16* __restrict__ kTp) {
  __shared__ float tile[32][33];
  int hz = blockIdx.z;
  int h = (hz < NH) ? hz : hz - NH;
  const float* src = ((hz < NH) ? qI : kI) + (size_t)h * ND * ND;
  u16* dst = ((hz < NH) ? qT : kTp) + (size_t)h * ND * ND;
  int c0 = blockIdx.x * 32, r0 = blockIdx.y * 32;
  int tx = threadIdx.x & 31, ty = threadIdx.x >> 5;
#pragma unroll
  for (int i = 0; i < 32; i += 8)
    tile[ty + i][tx] = src[(size_t)(r0 + ty + i) * ND + c0 + tx];
  __syncthreads();
#pragma unroll
  for (int i = 0; i < 32; i += 8)
    dst[(size_t)(c0 + ty + i) * ND + r0 + tx] = f2bf(tile[tx][ty + i]);
}

// ---------------- gemm_bt: C[M,N] = A[M,K] * B[N,K]^T (legacy 128^2 structure) ----------------
// Kept for MT (768^2 x12) and batched V2 (768x1024 x4) where its 4-blocks/CU overlap is fine.
template <bool BF16_OUT, int IM, int IN, int KDIM, int LDC>
__global__ __launch_bounds__(256, 4) void gemm_bt(
    const u16* __restrict__ A, const u16* __restrict__ Bm, void* __restrict__ Cv,
    long sAb, long sAn, long sAz,
    long sBb, long sBn, long sBz,
    long sCb, long sCn, long sCz,
    int p0) {
  constexpr int BK = 64;
  constexpr int MTILE = IM * 64;
  constexpr int NTILE = IN * 64;
  constexpr int CPR = BK / 8;
  constexpr int ACH = MTILE * CPR / 256;
  constexpr int BCH = NTILE * CPR / 256;
  __shared__ __align__(16) u16 As[MTILE * BK];
  __shared__ __align__(16) u16 Bs[NTILE * BK];

  int id = blockIdx.x + gridDim.x * (blockIdx.y + gridDim.y * blockIdx.z);
  int total = gridDim.x * gridDim.y * gridDim.z;
  int xx, yy, zz;
  if ((total & 7) == 0) {
    int per = total >> 3;
    int wk = (id & 7) * per + (id >> 3);
    xx = wk % gridDim.x;
    int g2 = wk / gridDim.x;
    yy = g2 % gridDim.y;
    zz = g2 / gridDim.y;
  } else {
    xx = blockIdx.x; yy = blockIdx.y; zz = blockIdx.z;
  }

  int g = p0 + zz;
  int b = g / NH, n = g % NH;
  A  += (size_t)b * sAb + (size_t)n * sAn + (size_t)zz * sAz;
  Bm += (size_t)b * sBb + (size_t)n * sBn + (size_t)zz * sBz;
  size_t cOff = (size_t)b * sCb + (size_t)n * sCn + (size_t)zz * sCz;

  int m0 = yy * MTILE, n0 = xx * NTILE;
  int t = threadIdx.x;
  int lane = t & 63, w = t >> 6;
  int m32 = lane & 31, kg = lane >> 5;
  int wm = w >> 1, wn = w & 1;

  const u16* gAb;
  const u16* gBb;
  {
    int r = t / CPR;
    int cc = (t & (CPR - 1)) ^ (r & 7);
    gAb = A + (size_t)(m0 + r) * KDIM + cc * 8;
    gBb = Bm + (size_t)(n0 + r) * KDIM + cc * 8;
  }

  f32x16 acc[IM][IN];
#pragma unroll
  for (int i = 0; i < IM; i++)
#pragma unroll
    for (int j = 0; j < IN; j++)
#pragma unroll
      for (int r = 0; r < 16; r++) acc[i][j][r] = 0.f;

#pragma unroll 1
  for (int k0 = 0; k0 < KDIM; k0 += BK) {
    __syncthreads();
#pragma unroll
    for (int u = 0; u < ACH; u++)
      load16_to_lds(gAb + (size_t)u * 32 * KDIM, &As[(size_t)(u * 256 + w * 64) * 8]);
    gAb += BK;
#pragma unroll
    for (int u = 0; u < BCH; u++)
      load16_to_lds(gBb + (size_t)u * 32 * KDIM, &Bs[(size_t)(u * 256 + w * 64) * 8]);
    gBb += BK;
    __syncthreads();

#pragma unroll
    for (int kc = 0; kc < 2; kc++) {
      short8 af[IM][2], bfr[IN][2];
#pragma unroll
      for (int i = 0; i < IM; i++) {
        int row = wm * (IM * 32) + i * 32 + m32;
#pragma unroll
        for (int h = 0; h < 2; h++) {
          int ck = (kc * 4 + h * 2 + kg) ^ (row & 7);
          af[i][h] = *(const short8*)&As[row * BK + ck * 8];
        }
      }
#pragma unroll
      for (int j = 0; j < IN; j++) {
        int row = wn * (IN * 32) + j * 32 + m32;
#pragma unroll
        for (int h = 0; h < 2; h++) {
          int ck = (kc * 4 + h * 2 + kg) ^ (row & 7);
          bfr[j][h] = *(const short8*)&Bs[row * BK + ck * 8];
        }
      }
#pragma unroll
      for (int i = 0; i < IM; i++)
#pragma unroll
        for (int j = 0; j < IN; j++) {
          acc[i][j] = __builtin_amdgcn_mfma_f32_32x32x16_bf16(af[i][0], bfr[j][0], acc[i][j], 0, 0, 0);
          acc[i][j] = __builtin_amdgcn_mfma_f32_32x32x16_bf16(af[i][1], bfr[j][1], acc[i][j], 0, 0, 0);
        }
    }
  }

#pragma unroll
  for (int i = 0; i < IM; i++) {
#pragma unroll
    for (int j = 0; j < IN; j++) {
      int colg = n0 + wn * (IN * 32) + j * 32 + m32;
#pragma unroll
      for (int r = 0; r < 16; r++) {
        int rowg = m0 + wm * (IM * 32) + i * 32 + (r & 3) + 8 * (r >> 2) + 4 * kg;
        float vv = acc[i][j][r];
        if (BF16_OUT) {
          ((u16*)Cv)[cOff + (size_t)rowg * LDC + colg] = f2bf(vv);
        } else {
          ((float*)Cv)[cOff + (size_t)rowg * LDC + colg] = vv;
        }
      }
    }
  }
}

// ---------------- gemm256_bt: 256x256 tile, 8 waves, counted-vmcnt pipeline ----------------
// C[M,N] = A[M,K] * B[N,K]^T, bf16 in, fp32 acc, 16x16x32 MFMA (16-row frags -> 2-way LDS
// conflicts only). Waves 2(M)x4(N); per-wave out rows {h*128+wm*64+[0,64)}, cols
// {g*128+wn*32+[0,32)}. Phases P0(h0,g0) P1(h0,g1) | M | P2(h1,g0) P3(h1,g1) | E.
// Stage ledger (buffers c = tk&1; 2 global_load_lds calls per 64-row slab per thread... one
// call = 512 thr x 16B = 64 rows):
//   prologue: tile0 full (8 calls) + Ah0(tile1) (2)  -> vmcnt(2): tile0 landed, Ah0(1) in flight
//   iter tk P0: stage Ah1(tk+1)+B(tk+1) -> other buf (6 calls; slots freed at E(tk-1))
//   iter tk P2: stage Ah0(tk+2) -> cur buf h0 (2 calls; slot freed at M(tk): phases 0-1
//               are the only readers of h0, all waves past M)
//   E(tk): vmcnt(2) -> tile tk+1 fully landed, Ah0(tk+2)'s 2 calls stay in flight (T4:
//          never drain to 0 in steady state). Raw s_barrier (no __syncthreads -> no forced
//          vmcnt(0) drain), sched_barrier(0) fences per rule #18.
template <bool BF16_OUT, int KDIM, int LDC>
__global__ __launch_bounds__(512, 2) void gemm256_bt(
    const u16* __restrict__ A, const u16* __restrict__ Bm, void* __restrict__ Cv,
    long sAb, long sAn, long sAz,
    long sBb, long sBn, long sBz,
    long sCb, long sCn, long sCz,
    int p0) {
  constexpr int BK = 64;
  constexpr int NT = KDIM / BK;
  static_assert(KDIM % BK == 0 && NT >= 3, "pipeline needs >=3 K-tiles");
  __shared__ __align__(16) u16 As[2][256 * BK];  // 64 KB
  __shared__ __align__(16) u16 Bs[2][256 * BK];  // 64 KB

  int id = blockIdx.x + gridDim.x * (blockIdx.y + gridDim.y * blockIdx.z);
  int total = gridDim.x * gridDim.y * gridDim.z;
  int xx, yy, zz;
  if ((total & 7) == 0) {
    int per = total >> 3;
    int wk = (id & 7) * per + (id >> 3);
    xx = wk % gridDim.x;
    int g2 = wk / gridDim.x;
    yy = g2 % gridDim.y;
    zz = g2 / gridDim.y;
  } else {
    xx = blockIdx.x; yy = blockIdx.y; zz = blockIdx.z;
  }

  int g = p0 + zz;
  int b = g / NH, n = g % NH;
  A  += (size_t)b * sAb + (size_t)n * sAn + (size_t)zz * sAz;
  Bm += (size_t)b * sBb + (size_t)n * sBn + (size_t)zz * sBz;
  size_t cOff = (size_t)b * sCb + (size_t)n * sCn + (size_t)zz * sCz;

  int m0 = yy * 256, n0 = xx * 256;
  int t = threadIdx.x;
  int lane = t & 63, w = t >> 6;
  int wm = w >> 2, wn = w & 3;
  int l15 = lane & 15, q4 = lane >> 4;

  // staging source bases: thread t covers row (t>>3) of each 64-row slab, source chunk
  // pre-swizzled so linear LDS dest + swizzled read = consistent involution (rule #21).
  int r0 = t >> 3;
  int cc0 = (t & 7) ^ (r0 & 7);
  const u16* gA = A + (size_t)(m0 + r0) * KDIM + cc0 * 8;
  const u16* gB = Bm + (size_t)(n0 + r0) * KDIM + cc0 * 8;

  u16* Ac = &As[0][0]; u16* Ao = &As[1][0];
  u16* Bc = &Bs[0][0]; u16* Bo = &Bs[1][0];
  int ldsOff = w * 64 * 8;  // per-wave base within a 512-thread call slab (u16 units)

#define STG_A(dst, k0, u) load16_to_lds(gA + (size_t)(u) * 64 * KDIM + (k0), (dst) + (u) * 512 * 8 + ldsOff)
#define STG_B(dst, k0, u) load16_to_lds(gB + (size_t)(u) * 64 * KDIM + (k0), (dst) + (u) * 512 * 8 + ldsOff)

#define READ_A(buf, H, dst) do { \
  _Pragma("unroll") for (int fm = 0; fm < 4; fm++) { \
    int row = (H) * 128 + wm * 64 + fm * 16 + l15; \
    _Pragma("unroll") for (int ks = 0; ks < 2; ks++) { \
      int ck = (ks * 4 + q4) ^ (row & 7); \
      dst[fm][ks] = *(const short8*)((buf) + row * 64 + ck * 8); \
    } \
  } \
} while (0)

#define READ_B(buf, G, dst) do { \
  _Pragma("unroll") for (int fn = 0; fn < 2; fn++) { \
    int row = (G) * 128 + wn * 32 + fn * 16 + l15; \
    _Pragma("unroll") for (int ks = 0; ks < 2; ks++) { \
      int ck = (ks * 4 + q4) ^ (row & 7); \
      dst[fn][ks] = *(const short8*)((buf) + row * 64 + ck * 8); \
    } \
  } \
} while (0)

#define MFMA_PH(H, G, AR, BR) do { \
  __builtin_amdgcn_s_setprio(1); \
  _Pragma("unroll") for (int ks = 0; ks < 2; ks++) \
    _Pragma("unroll") for (int fm = 0; fm < 4; fm++) \
      _Pragma("unroll") for (int fn = 0; fn < 2; fn++) \
        acc[H][G][fm][fn] = __builtin_amdgcn_mfma_f32_16x16x32_bf16(AR[fm][ks], BR[fn][ks], acc[H][G][fm][fn], 0, 0, 0); \
  __builtin_amdgcn_s_setprio(0); \
} while (0)

  f32x4 acc[2][2][4][2];
#pragma unroll
  for (int h = 0; h < 2; h++)
#pragma unroll
    for (int gg = 0; gg < 2; gg++)
#pragma unroll
      for (int fm = 0; fm < 4; fm++)
#pragma unroll
        for (int fn = 0; fn < 2; fn++)
          acc[h][gg][fm][fn] = (f32x4){0.f, 0.f, 0.f, 0.f};

  // prologue
  STG_A(Ac, 0, 0); STG_A(Ac, 0, 1); STG_A(Ac, 0, 2); STG_A(Ac, 0, 3);
  STG_B(Bc, 0, 0); STG_B(Bc, 0, 1); STG_B(Bc, 0, 2); STG_B(Bc, 0, 3);
  STG_A(Ao, BK, 0); STG_A(Ao, BK, 1);
  asm volatile("s_waitcnt vmcnt(2)" ::: "memory");
  __builtin_amdgcn_s_barrier();
  __builtin_amdgcn_sched_barrier(0);

#pragma unroll 1
  for (int tk = 0; tk < NT; ++tk) {
    short8 af[4][2], bf0[2][2], bf1[2][2];
    if (tk + 1 < NT) {
      int kn1 = (tk + 1) * BK;
      STG_A(Ao, kn1, 2); STG_A(Ao, kn1, 3);
      STG_B(Bo, kn1, 0); STG_B(Bo, kn1, 1); STG_B(Bo, kn1, 2); STG_B(Bo, kn1, 3);
    }
    READ_A(Ac, 0, af);
    READ_B(Bc, 0, bf0);
    MFMA_PH(0, 0, af, bf0);
    READ_B(Bc, 1, bf1);
    MFMA_PH(0, 1, af, bf1);
    // M barrier: releases cur h0 slot for the Ah0(tk+2) stage
    __builtin_amdgcn_sched_barrier(0);
    asm volatile("s_waitcnt lgkmcnt(0)" ::: "memory");
    __builtin_amdgcn_s_barrier();
    __builtin_amdgcn_sched_barrier(0);
    if (tk + 2 < NT) {
      int kn2 = (tk + 2) * BK;
      STG_A(Ac, kn2, 0); STG_A(Ac, kn2, 1);
    }
    READ_A(Ac, 1, af);
    MFMA_PH(1, 0, af, bf0);
    MFMA_PH(1, 1, af, bf1);
    if (tk + 1 < NT) {
      __builtin_amdgcn_sched_barrier(0);
      asm volatile("s_waitcnt lgkmcnt(0)" ::: "memory");
      if (tk + 2 < NT) {
        asm volatile("s_waitcnt vmcnt(2)" ::: "memory");  // tile tk+1 landed; 2 in flight
      } else {
        asm volatile("s_waitcnt vmcnt(0)" ::: "memory");  // epilogue drain
      }
      __builtin_amdgcn_s_barrier();
      __builtin_amdgcn_sched_barrier(0);
    }
    u16* tp = Ac; Ac = Ao; Ao = tp;
    tp = Bc; Bc = Bo; Bo = tp;
  }

  // epilogue: row = (lane>>4)*4 + r within 16x16 frag; col = lane&15
#pragma unroll
  for (int h = 0; h < 2; h++)
#pragma unroll
    for (int gg = 0; gg < 2; gg++)
#pragma unroll
      for (int fm = 0; fm < 4; fm++)
#pragma unroll
        for (int fn = 0; fn < 2; fn++) {
          int colg = n0 + gg * 128 + wn * 32 + fn * 16 + l15;
#pragma unroll
          for (int r = 0; r < 4; r++) {
            int rowg = m0 + h * 128 + wm * 64 + fm * 16 + q4 * 4 + r;
            float vv = acc[h][gg][fm][fn][r];
            if (BF16_OUT) {
              ((u16*)Cv)[cOff + (size_t)rowg * LDC + colg] = f2bf(vv);
            } else {
              ((float*)Cv)[cOff + (size_t)rowg * LDC + colg] = vv;
            }
          }
        }
#undef STG_A
#undef STG_B
#undef READ_A
#undef READ_B
#undef MFMA_PH
}

// ---------------- fused softmax + PV ----------------
// V2 is now a FULL [48][NDH][NL] buffer (batched GEMM) -> index by global g, not local zz.
__global__ __launch_bounds__(256) void softmax_pv_kernel(
    const u16* __restrict__ Sb, const u16* __restrict__ V2, float* __restrict__ out,
    int p0) {
  __shared__ __align__(16) u16 Ps[64 * 128];  // 16 KB
  __shared__ __align__(16) u16 Vs[64 * 128];  // 16 KB

  int id = blockIdx.x + gridDim.x * blockIdx.y;
  int total = gridDim.x * gridDim.y;
  int xx, zz;
  if ((total & 7) == 0) {
    int per = total >> 3;
    int wk = (id & 7) * per + (id >> 3);
    xx = wk & 15; zz = wk >> 4;
  } else {
    xx = blockIdx.x; zz = blockIdx.y;
  }

  int g = p0 + zz;
  int b = g / NH, n = g % NH;
  const u16* S = Sb + (size_t)zz * NL * NL;
  const u16* V = V2 + (size_t)g * NDH * NL;

  int l0 = xx * 64;
  int t = threadIdx.x;
  int lane = t & 63, w = t >> 6;
  int row16 = lane & 15, q = lane >> 4;
  int rs = row16 & 7;

  f32x4 acc[5];
#pragma unroll
  for (int j = 0; j < 5; j++) acc[j] = (f32x4){0.f, 0.f, 0.f, 0.f};

  short8 onesf;
  {
    short val = (row16 == 0) ? (short)0x3F80 : (short)0;
#pragma unroll
    for (int e = 0; e < 8; e++) onesf[e] = val;
  }

  const u16* ssrc[4];
  const u16* vsrc[4];
#pragma unroll
  for (int u = 0; u < 4; u++) {
    int c = u * 256 + t;
    int r = c >> 4, cc = (c & 15) ^ (r & 7);
    ssrc[u] = S + (size_t)(l0 + r) * NL + cc * 8;
    vsrc[u] = V + (size_t)r * NL + cc * 8;
  }

#pragma unroll 1
  for (int mt = 0; mt < 8; mt++) {
    int mo = mt * 128;
    __syncthreads();
#pragma unroll
    for (int u = 0; u < 4; u++)
      load16_to_lds(ssrc[u] + mo, &Ps[(size_t)(u * 256 + w * 64) * 8]);
#pragma unroll
    for (int u = 0; u < 4; u++)
      load16_to_lds(vsrc[u] + mo, &Vs[(size_t)(u * 256 + w * 64) * 8]);
    __syncthreads();

#pragma unroll
    for (int kk = 0; kk < 4; kk++) {
      int ch = ((kk * 4 + q) ^ rs) * 16;
      int lrow = w * 16 + row16;
      short8 raw = *(const short8*)((const char*)Ps + lrow * 256 + ch);
      short8 af;
#pragma unroll
      for (int e = 0; e < 8; e++) af[e] = (short)f2bf(__expf(bf2f((u16)raw[e])));
      short8 bfr[4];
#pragma unroll
      for (int j = 0; j < 4; j++) {
        int dh = j * 16 + row16;
        bfr[j] = *(const short8*)((const char*)Vs + dh * 256 + ch);
      }
#pragma unroll
      for (int j = 0; j < 4; j++)
        acc[j] = __builtin_amdgcn_mfma_f32_16x16x32_bf16(af, bfr[j], acc[j], 0, 0, 0);
      acc[4] = __builtin_amdgcn_mfma_f32_16x16x32_bf16(af, onesf, acc[4], 0, 0, 0);
    }
  }

#pragma unroll
  for (int r = 0; r < 4; r++) {
    float sum = __shfl(acc[4][r], lane & 48, 64);
    float inv = 1.0f / sum;
    int row = l0 + w * 16 + q * 4 + r;
    float* op = out + ((size_t)b * NL + row) * ND + n * NDH;
#pragma unroll
    for (int j = 0; j < 4; j++)
      op[j * 16 + row16] = acc[j][r] * inv;
  }
}

extern "C" void kernel_launch(void* const* d_in, const int* in_sizes, int n_in,
                              void* d_out, int out_size, void* d_ws, size_t ws_size,
                              hipStream_t stream) {
  (void)in_sizes; (void)n_in; (void)out_size;
  const float* x  = (const float*)d_in[0];
  const float* kI = (const float*)d_in[1];
  const float* qI = (const float*)d_in[2];
  const float* vI = (const float*)d_in[3];
  float* out = (float*)d_out;

  size_t off = 0;
  char* wsb = (char*)d_ws;
  auto alloc = [&](size_t bytes) -> char* {
    char* p = wsb + off;
    off += (bytes + 255) & ~(size_t)255;
    return p;
  };
  u16* xb = (u16*)alloc((size_t)NB * NL * ND * 2);        // bf16 x, [b][l][d]
  u16* qT = (u16*)alloc((size_t)NH * ND * ND * 2);        // q^T per head: [n][d][c]
  u16* kT = (u16*)alloc((size_t)NH * ND * ND * 2);        // k^T per head: [n][e][c]
  u16* vb = (u16*)alloc((size_t)NH * NDH * ND * 2);       // bf16 v, [n][dh][d] == [768][768]
  u16* MT = (u16*)alloc((size_t)NH * ND * ND * 2);        // MT[n][e][d] = M[d][e]
  u16* V2 = (u16*)alloc((size_t)NB * NH * NDH * NL * 2);  // FULL [z][dh][m], 6.3 MB
  size_t fixedSz = off;
  const size_t perPair = (size_t)NL * ND * 2 + (size_t)NL * NL * 2;
  int chunk = NB * NH;
  if (fixedSz + (size_t)chunk * perPair > ws_size) {
    size_t avail = ws_size > fixedSz ? ws_size - fixedSz : 0;
    chunk = (int)(avail / perPair);
    if (chunk < 1) chunk = 1;
    if (chunk > NB * NH) chunk = NB * NH;
  }
  u16* T  = (u16*)alloc((size_t)chunk * NL * ND * 2);   // [z][l][e]
  u16* Sb = (u16*)alloc((size_t)chunk * NL * NL * 2);   // [z][l][m] logits

  const long DD  = (long)ND * ND;
  const long LD  = (long)NL * ND;
  const long LL  = (long)NL * NL;
  const long DHL = (long)NDH * NL;

  {
    int n4 = NB * NL * ND / 4;
    cast_bf16_kernel<<<dim3((n4 + 255) / 256), dim3(256), 0, stream>>>(x, xb, n4);
    int n4v = NH * NDH * ND / 4;
    cast_bf16_kernel<<<dim3((n4v + 255) / 256), dim3(256), 0, stream>>>(vI, vb, n4v);
  }
  transpose_cast2_kernel<<<dim3(24, 24, 2 * NH), dim3(256), 0, stream>>>(qI, kI, qT, kT);

  // MT[n][e][d] = sum_c kT[n][e][c] * qT[n][d][c]   (768x768, K=768)
  gemm_bt<true, 2, 2, 768, ND><<<dim3(6, 6, NH), dim3(256), 0, stream>>>(
      kT, qT, MT,
      0, DD, 0,  0, DD, 0,  0, DD, 0, 0);

  // Batched V2: per batch b, V2[b*NH.. ][dh][m] = vb(flat [768][768]) * xb[b]^T
  // (768x1024, K=768) -> one 128^2-tile GEMM per b instead of 48 slices of 64^2 tiles.
  gemm_bt<true, 2, 2, 768, NL><<<dim3(8, 6, NB), dim3(256), 0, stream>>>(
      vb, xb, V2,
      0, 0, 0,  0, 0, LD,  0, 0, (long)NH * DHL, 0);

  for (int p0 = 0; p0 < NB * NH; p0 += chunk) {
    int c = NB * NH - p0;
    if (c > chunk) c = chunk;
    // T[z][l][e] = sum_d xb[b][l][d] * MT[n][e][d]   (1024x768, K=768) — 256^2 pipeline
    gemm256_bt<true, 768, ND><<<dim3(3, 4, c), dim3(512), 0, stream>>>(
        xb, MT, T,
        LD, 0, 0,  0, DD, 0,  0, 0, LD, p0);
    // Sb[z][l][m] = sum_e T[z][l][e] * xb[b][m][e]   (1024x1024, K=768) — 256^2 pipeline
    gemm256_bt<true, 768, NL><<<dim3(4, 4, c), dim3(512), 0, stream>>>(
        T, xb, Sb,
        0, 0, LD,  LD, 0, 0,  0, 0, LL, p0);
    // fused softmax + PV -> writes out directly
    softmax_pv_kernel<<<dim3(16, c), dim3(256), 0, stream>>>(Sb, V2, out, p0);
  }
}